// Round 12
// baseline (586.365 us; speedup 1.0000x reference)
//
#include <hip/hip_runtime.h>
#include <hip/hip_bf16.h>
#include <stdint.h>
#include <math.h>

// SparseMoeBlock: 8 experts, top-2, H=2048, I=1408, T=8192, fp32 in/out.
// R12 = R11 + Wd-conversion folded into gemm1's idle blocks (atomic
// work-stealing chunks; deterministic — each chunk converted exactly once;
// gemm2 reads wd_bf only after gemm1's grid fully retires). cvtw converts
// Wgu only. launch_bounds(256,2) on both GEMMs.

#define E_ 8
#define H_ 2048
#define I_ 1408
#define T_ 8192
#define NSLOT (T_ * 2)
#define NBLK 64               // count/scatter blocks (NSLOT/256)
#define NCHUNK 2816           // Wd vec8-chunks: 8*2048*1408/8/1024

typedef __bf16 bf16;
typedef bf16 bf16x4 __attribute__((ext_vector_type(4)));
typedef bf16 bf16x8 __attribute__((ext_vector_type(8)));
typedef float f32x4 __attribute__((ext_vector_type(4)));

__device__ inline void gl2lds16(const void* g, void* l) {
  __builtin_amdgcn_global_load_lds(
      (const __attribute__((address_space(1))) unsigned int*)g,
      (__attribute__((address_space(3))) unsigned int*)l, 16, 0, 0);
}

// ------------- fp32 -> bf16 conversion (Wgu only) -------------
__global__ __launch_bounds__(256) void cvt_k(const float* __restrict__ in,
                                             bf16* __restrict__ out, int n8) {
  int stride = gridDim.x * blockDim.x;
  for (int i = blockIdx.x * blockDim.x + threadIdx.x; i < n8; i += stride) {
    const float4* p = (const float4*)in + (size_t)i * 2;
    float4 a = p[0], b = p[1];
    bf16x8 o;
    o[0] = (bf16)a.x; o[1] = (bf16)a.y; o[2] = (bf16)a.z; o[3] = (bf16)a.w;
    o[4] = (bf16)b.x; o[5] = (bf16)b.y; o[6] = (bf16)b.z; o[7] = (bf16)b.w;
    *((bf16x8*)out + i) = o;
  }
}

// ------------- router: logits, top-2 weights, X -> bf16 (no atomics) -------
__global__ __launch_bounds__(256) void router_k(const float* __restrict__ X,
                                                const float* __restrict__ R,
                                                bf16* __restrict__ xbf,
                                                int* __restrict__ sel,
                                                float* __restrict__ wts) {
  int lane = threadIdx.x & 63;
  int t = blockIdx.x * 4 + (threadIdx.x >> 6);
  const float4* x4 = (const float4*)(X + (size_t)t * H_);
  bf16x4* xb4 = (bf16x4*)(xbf + (size_t)t * H_);
  float acc[E_];
#pragma unroll
  for (int e = 0; e < E_; ++e) acc[e] = 0.f;
#pragma unroll
  for (int i = 0; i < H_ / 256; ++i) {
    float4 x = x4[i * 64 + lane];
    bf16x4 xo; xo[0] = (bf16)x.x; xo[1] = (bf16)x.y; xo[2] = (bf16)x.z; xo[3] = (bf16)x.w;
    xb4[i * 64 + lane] = xo;
#pragma unroll
    for (int e = 0; e < E_; ++e) {
      float4 r = ((const float4*)(R + (size_t)e * H_))[i * 64 + lane];
      acc[e] += x.x * r.x + x.y * r.y + x.z * r.z + x.w * r.w;
    }
  }
#pragma unroll
  for (int e = 0; e < E_; ++e)
#pragma unroll
    for (int off = 32; off > 0; off >>= 1) acc[e] += __shfl_xor(acc[e], off);
  if (lane == 0) {
    int e1 = 0; float l1 = acc[0];
#pragma unroll
    for (int e = 1; e < E_; ++e) if (acc[e] > l1) { l1 = acc[e]; e1 = e; }
    int e2 = -1; float l2 = -3.4e38f;
#pragma unroll
    for (int e = 0; e < E_; ++e) if (e != e1 && acc[e] > l2) { l2 = acc[e]; e2 = e; }
    float d = expf(l2 - l1);
    float inv = 1.f / (1.f + d);
    sel[2 * t] = e1; sel[2 * t + 1] = e2;
    wts[2 * t] = inv; wts[2 * t + 1] = d * inv;
  }
}

// ------------- count: per-block expert histogram (LDS atomics only) -------
__global__ __launch_bounds__(256) void count_k(const int* __restrict__ sel,
                                               int* __restrict__ blockHist) {
  __shared__ int h[E_];
  int t = threadIdx.x;
  if (t < E_) h[t] = 0;
  __syncthreads();
  atomicAdd(&h[sel[blockIdx.x * 256 + t]], 1);
  __syncthreads();
  if (t < E_) blockHist[blockIdx.x * E_ + t] = h[t];
}

// ------------- plan: counts, offsets, per-block scatter bases -------
// ctl[0..7]=counts, ctl[8..15]=offsets.
__global__ __launch_bounds__(64) void plan_k(const int* __restrict__ blockHist,
                                             int* __restrict__ ctl,
                                             int* __restrict__ blockBase) {
  __shared__ int cnts[E_], offs[E_];
  int t = threadIdx.x;
  if (t < E_) {
    int c = 0;
    for (int b = 0; b < NBLK; ++b) c += blockHist[b * E_ + t];
    cnts[t] = c; ctl[t] = c;
  }
  __syncthreads();
  if (t == 0) {
    int off = 0;
    for (int e = 0; e < E_; ++e) { offs[e] = off; ctl[8 + e] = off; off += cnts[e]; }
  }
  __syncthreads();
  if (t < E_) {  // per-block scatter bases: column-wise exclusive scan
    int run = offs[t];
    for (int b = 0; b < NBLK; ++b) {
      blockBase[b * E_ + t] = run;
      run += blockHist[b * E_ + t];
    }
  }
}

// ------------- scatter: deterministic, atomic-free (ballot ranks) -------
__global__ __launch_bounds__(256) void scatter_k(const int* __restrict__ sel,
                                                 const float* __restrict__ wts,
                                                 const int* __restrict__ blockBase,
                                                 int* __restrict__ tok,
                                                 float* __restrict__ sw,
                                                 int* __restrict__ inv) {
  __shared__ int wcnt[4][E_];
  int t = threadIdx.x;
  int lane = t & 63, w = t >> 6;
  int i = blockIdx.x * 256 + t;
  int e = sel[i];
  unsigned long long below = (lane == 63) ? ~0ull >> 1 : (1ull << lane) - 1;
  int myrank = 0;
#pragma unroll
  for (int e0 = 0; e0 < E_; ++e0) {
    unsigned long long m = __ballot(e == e0);
    if (e == e0) myrank = __popcll(m & below);
    if (lane == 0) wcnt[w][e0] = __popcll(m);
  }
  __syncthreads();
  int pos = blockBase[blockIdx.x * E_ + e] + myrank;
#pragma unroll
  for (int w2 = 0; w2 < 3; ++w2)
    if (w2 < w) pos += wcnt[w2][e];
  tok[pos] = i >> 1;
  sw[pos] = wts[i];
  inv[i] = pos;
}

// ---------------- GEMM1: act = silu(Xg @ Wg^T) * (Xg @ Wu^T) ----------------
// R2 champion: 128 token-rows x 64 j (gate+up panels), BK=64, 4 waves (2x2),
// 2-phase dbuf, 64KB LDS -> 2 blocks/CU. Expert-per-XCD, m outer, j inner.
// Idle blocks (m0 >= cnt) convert Wd fp32->bf16 via work-stealing chunks.
__global__ __launch_bounds__(256, 2) void gemm1_k(const bf16* __restrict__ Xb,
                                                  const bf16* __restrict__ Wgu,
                                                  const int* __restrict__ ctl,
                                                  const int* __restrict__ tok,
                                                  bf16* __restrict__ act,
                                                  const float* __restrict__ Wd32,
                                                  bf16* __restrict__ wdbf,
                                                  int* __restrict__ cvtc) {
  constexpr int NJ = I_ / 64;        // 22
  constexpr int NM = T_ / 128;       // 64
  constexpr int NB = NJ * NM * E_;   // 11264
  const int L0 = ((int)blockIdx.x & 7) * (NB >> 3) + ((int)blockIdx.x >> 3);
  const int e = L0 / (NJ * NM);
  const int rem = L0 - e * (NJ * NM);
  const int m0 = (rem / NJ) * 128;   // m outer, j inner -> A-tile L2-hot
  const int j0 = (rem % NJ) * 64;
  const int cnt = ctl[e];
  const int t = threadIdx.x;

  if (m0 >= cnt) {
    // idle tile -> convert Wd chunks (1024 bf16x8 per chunk)
    __shared__ int sc;
    for (;;) {
      if (t == 0) sc = atomicAdd(cvtc, 1);
      __syncthreads();
      int c = sc;
      __syncthreads();
      if (c >= NCHUNK) return;
#pragma unroll
      for (int k = 0; k < 4; ++k) {
        size_t v = (size_t)c * 1024 + k * 256 + t;
        const float4* p = (const float4*)Wd32 + v * 2;
        float4 x = p[0], y = p[1];
        bf16x8 o;
        o[0] = (bf16)x.x; o[1] = (bf16)x.y; o[2] = (bf16)x.z; o[3] = (bf16)x.w;
        o[4] = (bf16)y.x; o[5] = (bf16)y.y; o[6] = (bf16)y.z; o[7] = (bf16)y.w;
        *((bf16x8*)wdbf + v) = o;
      }
    }
  }
  const int base = ctl[8 + e];

  __shared__ alignas(16) bf16 lA[2][128 * 64];
  __shared__ alignas(16) bf16 lBg[2][64 * 64];
  __shared__ alignas(16) bf16 lBu[2][64 * 64];

  const int lane = t & 63;
  const int wr = (t >> 7) & 1;
  const int wc = (t >> 6) & 1;
  const int lo = lane & 15, hi = lane >> 4;
  const bf16* wg = Wgu + (size_t)e * (2 * I_) * H_;

  // staging; XOR swizzle on the GLOBAL source chunk, LDS dest linear
  const bf16* asrc[4]; int aoff[4];
#pragma unroll
  for (int c = 0; c < 4; ++c) {
    int L = c * 256 + t;
    int row = L >> 3, cc = (L & 7) ^ (row & 7);
    int r = m0 + row; if (r >= cnt) r = cnt - 1;
    asrc[c] = Xb + (size_t)tok[base + r] * H_ + cc * 8;
    aoff[c] = L * 16;
  }
  const bf16* gsrc[2]; const bf16* usrc[2]; int boff[2];
#pragma unroll
  for (int c = 0; c < 2; ++c) {
    int L = c * 256 + t;
    int row = L >> 3, cc = (L & 7) ^ (row & 7);
    gsrc[c] = wg + (size_t)(j0 + row) * H_ + cc * 8;
    usrc[c] = wg + (size_t)(I_ + j0 + row) * H_ + cc * 8;
    boff[c] = L * 16;
  }

#define STG1(b, k)                                                \
  {                                                               \
    _Pragma("unroll")                                             \
    for (int c = 0; c < 4; ++c)                                   \
      gl2lds16(asrc[c] + (k), (char*)lA[b] + aoff[c]);            \
    _Pragma("unroll")                                             \
    for (int c = 0; c < 2; ++c) {                                 \
      gl2lds16(gsrc[c] + (k), (char*)lBg[b] + boff[c]);           \
      gl2lds16(usrc[c] + (k), (char*)lBu[b] + boff[c]);           \
    }                                                             \
  }

  f32x4 zero = {0.f, 0.f, 0.f, 0.f};
  f32x4 ag[4][2], au[4][2];
#pragma unroll
  for (int m = 0; m < 4; ++m)
#pragma unroll
    for (int n = 0; n < 2; ++n) { ag[m][n] = zero; au[m][n] = zero; }

  STG1(0, 0);
  __syncthreads();

  for (int k0 = 0; k0 < H_; k0 += 128) {
#pragma unroll
    for (int p = 0; p < 2; ++p) {
      const int kc = k0 + p * 64;
      if (kc + 64 < H_) STG1(p ^ 1, kc + 64);   // prefetch next K-tile
#pragma unroll
      for (int kk = 0; kk < 2; ++kk) {
        const int chunk = kk * 4 + hi;
        bf16x8 af[4], bg[2], bu[2];
#pragma unroll
        for (int m = 0; m < 4; ++m) {
          int row = wr * 64 + m * 16 + lo;
          af[m] = *(const bf16x8*)((const char*)lA[p] + row * 128 + ((chunk ^ (row & 7)) * 16));
        }
#pragma unroll
        for (int n = 0; n < 2; ++n) {
          int row = wc * 32 + n * 16 + lo;
          int sw2 = (chunk ^ (row & 7)) * 16;
          bg[n] = *(const bf16x8*)((const char*)lBg[p] + row * 128 + sw2);
          bu[n] = *(const bf16x8*)((const char*)lBu[p] + row * 128 + sw2);
        }
#pragma unroll
        for (int m = 0; m < 4; ++m)
#pragma unroll
          for (int n = 0; n < 2; ++n) {
            ag[m][n] = __builtin_amdgcn_mfma_f32_16x16x32_bf16(af[m], bg[n], ag[m][n], 0, 0, 0);
            au[m][n] = __builtin_amdgcn_mfma_f32_16x16x32_bf16(af[m], bu[n], au[m][n], 0, 0, 0);
          }
      }
      __syncthreads();
    }
  }
#undef STG1

#pragma unroll
  for (int m = 0; m < 4; ++m)
#pragma unroll
    for (int r = 0; r < 4; ++r) {
      int row = m0 + wr * 64 + m * 16 + hi * 4 + r;
      if (row < cnt) {
        bf16* dst = act + (size_t)(base + row) * I_ + j0 + wc * 32 + lo;
#pragma unroll
        for (int n = 0; n < 2; ++n) {
          float g = ag[m][n][r], u = au[m][n][r];
          dst[n * 16] = (bf16)(g / (1.f + __expf(-g)) * u);
        }
      }
    }
}

// ---------------- GEMM2: y[slot] = w * (act @ Wd^T), bf16, no atomics ------
// 128 slot-rows x 128 H-cols, BK=64, 4 waves (2x2), 2-phase dbuf, 64KB LDS.
__global__ __launch_bounds__(256, 2) void gemm2_k(const bf16* __restrict__ act,
                                                  const bf16* __restrict__ Wd,
                                                  const int* __restrict__ ctl,
                                                  const float* __restrict__ sw,
                                                  bf16* __restrict__ y) {
  constexpr int NJ = H_ / 128;       // 16
  constexpr int NM = T_ / 128;       // 64
  constexpr int NB = NJ * NM * E_;   // 8192
  const int L0 = ((int)blockIdx.x & 7) * (NB >> 3) + ((int)blockIdx.x >> 3);
  const int e = L0 / (NJ * NM);
  const int rem = L0 - e * (NJ * NM);
  const int m0 = (rem / NJ) * 128;
  const int n0 = (rem % NJ) * 128;
  const int cnt = ctl[e];
  if (m0 >= cnt) return;
  const int base = ctl[8 + e];

  __shared__ alignas(16) bf16 lA[2][128 * 64];
  __shared__ alignas(16) bf16 lB[2][128 * 64];

  const int t = threadIdx.x;
  const int lane = t & 63;
  const int wr = (t >> 7) & 1;
  const int wc = (t >> 6) & 1;
  const int lo = lane & 15, hi = lane >> 4;
  const bf16* wd = Wd + (size_t)e * H_ * I_;

  const bf16* asrc[4]; int aoff[4];
#pragma unroll
  for (int c = 0; c < 4; ++c) {
    int L = c * 256 + t;
    int row = L >> 3, cc = (L & 7) ^ (row & 7);
    int r = m0 + row; if (r >= cnt) r = cnt - 1;
    asrc[c] = act + (size_t)(base + r) * I_ + cc * 8;
    aoff[c] = L * 16;
  }
  const bf16* bsrc[4]; int boff[4];
#pragma unroll
  for (int c = 0; c < 4; ++c) {
    int L = c * 256 + t;
    int row = L >> 3, cc = (L & 7) ^ (row & 7);
    bsrc[c] = wd + (size_t)(n0 + row) * I_ + cc * 8;
    boff[c] = L * 16;
  }

#define STG2(b, k)                                                \
  {                                                               \
    _Pragma("unroll")                                             \
    for (int c = 0; c < 4; ++c)                                   \
      gl2lds16(asrc[c] + (k), (char*)lA[b] + aoff[c]);            \
    _Pragma("unroll")                                             \
    for (int c = 0; c < 4; ++c)                                   \
      gl2lds16(bsrc[c] + (k), (char*)lB[b] + boff[c]);            \
  }

  f32x4 zero = {0.f, 0.f, 0.f, 0.f};
  f32x4 acc[4][4];
#pragma unroll
  for (int m = 0; m < 4; ++m)
#pragma unroll
    for (int n = 0; n < 4; ++n) acc[m][n] = zero;

  STG2(0, 0);
  __syncthreads();

  for (int k0 = 0; k0 < I_; k0 += 128) {
#pragma unroll
    for (int p = 0; p < 2; ++p) {
      const int kc = k0 + p * 64;
      if (kc + 64 < I_) STG2(p ^ 1, kc + 64);
#pragma unroll
      for (int kk = 0; kk < 2; ++kk) {
        const int chunk = kk * 4 + hi;
        bf16x8 af[4], bb[4];
#pragma unroll
        for (int m = 0; m < 4; ++m) {
          int row = wr * 64 + m * 16 + lo;
          af[m] = *(const bf16x8*)((const char*)lA[p] + row * 128 + ((chunk ^ (row & 7)) * 16));
        }
#pragma unroll
        for (int n = 0; n < 4; ++n) {
          int row = wc * 64 + n * 16 + lo;
          bb[n] = *(const bf16x8*)((const char*)lB[p] + row * 128 + ((chunk ^ (row & 7)) * 16));
        }
#pragma unroll
        for (int m = 0; m < 4; ++m)
#pragma unroll
          for (int n = 0; n < 4; ++n)
            acc[m][n] = __builtin_amdgcn_mfma_f32_16x16x32_bf16(af[m], bb[n], acc[m][n], 0, 0, 0);
      }
      __syncthreads();
    }
  }
#undef STG2

#pragma unroll
  for (int m = 0; m < 4; ++m)
#pragma unroll
    for (int r = 0; r < 4; ++r) {
      int row = m0 + wr * 64 + m * 16 + hi * 4 + r;
      if (row < cnt) {
        float w = sw[base + row];
        bf16* dst = y + (size_t)(base + row) * H_ + n0 + wc * 64 + lo;
#pragma unroll
        for (int n = 0; n < 4; ++n) dst[n * 16] = (bf16)(w * acc[m][n][r]);
      }
    }
}

// ---------------- combine: out[t] = y[inv[2t]] + y[inv[2t+1]] ----------------
__global__ __launch_bounds__(256) void combine_k(const bf16* __restrict__ y,
                                                 const int* __restrict__ inv,
                                                 float* __restrict__ out) {
  int idx = blockIdx.x * 256 + threadIdx.x;  // one bf16x8 chunk per thread
  int t = idx >> 8;                          // H_/8 = 256 chunks per token
  int c = idx & 255;
  int i1 = inv[2 * t], i2 = inv[2 * t + 1];
  bf16x8 a = *((const bf16x8*)(y + (size_t)i1 * H_) + c);
  bf16x8 b = *((const bf16x8*)(y + (size_t)i2 * H_) + c);
  float* op = out + (size_t)t * H_ + c * 8;
#pragma unroll
  for (int k = 0; k < 8; ++k) op[k] = (float)a[k] + (float)b[k];
}

// ---------------- host launch ----------------
extern "C" void kernel_launch(void* const* d_in, const int* in_sizes, int n_in,
                              void* d_out, int out_size, void* d_ws, size_t ws_size,
                              hipStream_t stream) {
  const float* X = (const float*)d_in[0];
  const float* R = (const float*)d_in[1];
  const float* Wgu = (const float*)d_in[2];
  const float* Wd = (const float*)d_in[3];
  float* out = (float*)d_out;

  char* ws = (char*)d_ws;
  size_t o = 0;
  auto alloc = [&](size_t sz) { void* p = ws + o; o += (sz + 255) & ~(size_t)255; return p; };
  bf16* wgu_bf = (bf16*)alloc(sizeof(bf16) * (size_t)E_ * 2 * I_ * H_);
  bf16* wd_bf  = (bf16*)alloc(sizeof(bf16) * (size_t)E_ * H_ * I_);
  bf16* xbf    = (bf16*)alloc(sizeof(bf16) * (size_t)T_ * H_);
  bf16* actb   = (bf16*)alloc(sizeof(bf16) * (size_t)NSLOT * I_);
  int* sel     = (int*)alloc(4 * NSLOT);
  float* wts   = (float*)alloc(4 * NSLOT);
  int* tokb    = (int*)alloc(4 * NSLOT);
  float* swb   = (float*)alloc(4 * NSLOT);
  int* invb    = (int*)alloc(4 * NSLOT);
  int* ctl     = (int*)alloc(4 * 32);
  int* bh      = (int*)alloc(4 * NBLK * E_);
  int* bb      = (int*)alloc(4 * NBLK * E_);
  int* cvtc    = (int*)alloc(4 * 64);
  // y (NSLOT x H bf16, 67 MB) aliases wgu_bf (92 MB), dead after gemm1
  bf16* yb = wgu_bf;

  hipMemsetAsync(cvtc, 0, 4, stream);

  cvt_k<<<2048, 256, 0, stream>>>(Wgu, wgu_bf, (int)((size_t)E_ * 2 * I_ * H_ / 8));
  router_k<<<T_ / 4, 256, 0, stream>>>(X, R, xbf, sel, wts);
  count_k<<<NBLK, 256, 0, stream>>>(sel, bh);
  plan_k<<<1, 64, 0, stream>>>(bh, ctl, bb);
  scatter_k<<<NBLK, 256, 0, stream>>>(sel, wts, bb, tokb, swb, invb);
  gemm1_k<<<(I_ / 64) * (T_ / 128) * E_, 256, 0, stream>>>(xbf, wgu_bf, ctl, tokb,
                                                           actb, Wd, wd_bf, cvtc);
  gemm2_k<<<(H_ / 128) * (T_ / 128) * E_, 256, 0, stream>>>(actb, wd_bf, ctl, swb, yb);
  combine_k<<<T_ * H_ / 2048, 256, 0, stream>>>(yb, invb, out);
}

// Round 13
// 519.086 us; speedup vs baseline: 1.1296x; 1.1296x over previous
//
#include <hip/hip_runtime.h>
#include <hip/hip_bf16.h>
#include <stdint.h>
#include <math.h>

// SparseMoeBlock: 8 experts, top-2, H=2048, I=1408, T=8192, fp32 in/out.
// R13 = exact revert to R11 (best measured: 519us). gemm1 = R2 champion
// (128x64 gate+up, 2-phase dbuf, 4 waves, 64KB LDS, expert-per-XCD,
// m-outer/j-inner). gemm2 = same structure, atomic-free bf16 y-write
// (weight folded) + combine. Atomic-free routing, fused weight cvt.
// R12's fused Wd-conversion REVERTED: converter blocks displaced GEMM
// blocks and contended for L2/HBM (gemm1 260->343, FETCH 340->530 MB).

#define E_ 8
#define H_ 2048
#define I_ 1408
#define T_ 8192
#define NSLOT (T_ * 2)
#define NBLK 64               // count/scatter blocks (NSLOT/256)

typedef __bf16 bf16;
typedef bf16 bf16x4 __attribute__((ext_vector_type(4)));
typedef bf16 bf16x8 __attribute__((ext_vector_type(8)));
typedef float f32x4 __attribute__((ext_vector_type(4)));

__device__ inline void gl2lds16(const void* g, void* l) {
  __builtin_amdgcn_global_load_lds(
      (const __attribute__((address_space(1))) unsigned int*)g,
      (__attribute__((address_space(3))) unsigned int*)l, 16, 0, 0);
}

// ------------- fused fp32 -> bf16 conversion for both weight tensors -------
__global__ __launch_bounds__(256) void cvtw_k(const float* __restrict__ a, int n8a,
                                              const float* __restrict__ b, int n8b,
                                              bf16* __restrict__ oa,
                                              bf16* __restrict__ ob) {
  int stride = gridDim.x * blockDim.x;
  int ntot = n8a + n8b;
  for (int i = blockIdx.x * blockDim.x + threadIdx.x; i < ntot; i += stride) {
    const float* src; bf16* dst; int k;
    if (i < n8a) { src = a; dst = oa; k = i; }
    else         { src = b; dst = ob; k = i - n8a; }
    const float4* p = (const float4*)src + (size_t)k * 2;
    float4 x = p[0], y = p[1];
    bf16x8 o;
    o[0] = (bf16)x.x; o[1] = (bf16)x.y; o[2] = (bf16)x.z; o[3] = (bf16)x.w;
    o[4] = (bf16)y.x; o[5] = (bf16)y.y; o[6] = (bf16)y.z; o[7] = (bf16)y.w;
    *((bf16x8*)dst + k) = o;
  }
}

// ------------- router: logits, top-2 weights, X -> bf16 (no atomics) -------
__global__ __launch_bounds__(256) void router_k(const float* __restrict__ X,
                                                const float* __restrict__ R,
                                                bf16* __restrict__ xbf,
                                                int* __restrict__ sel,
                                                float* __restrict__ wts) {
  int lane = threadIdx.x & 63;
  int t = blockIdx.x * 4 + (threadIdx.x >> 6);
  const float4* x4 = (const float4*)(X + (size_t)t * H_);
  bf16x4* xb4 = (bf16x4*)(xbf + (size_t)t * H_);
  float acc[E_];
#pragma unroll
  for (int e = 0; e < E_; ++e) acc[e] = 0.f;
#pragma unroll
  for (int i = 0; i < H_ / 256; ++i) {
    float4 x = x4[i * 64 + lane];
    bf16x4 xo; xo[0] = (bf16)x.x; xo[1] = (bf16)x.y; xo[2] = (bf16)x.z; xo[3] = (bf16)x.w;
    xb4[i * 64 + lane] = xo;
#pragma unroll
    for (int e = 0; e < E_; ++e) {
      float4 r = ((const float4*)(R + (size_t)e * H_))[i * 64 + lane];
      acc[e] += x.x * r.x + x.y * r.y + x.z * r.z + x.w * r.w;
    }
  }
#pragma unroll
  for (int e = 0; e < E_; ++e)
#pragma unroll
    for (int off = 32; off > 0; off >>= 1) acc[e] += __shfl_xor(acc[e], off);
  if (lane == 0) {
    int e1 = 0; float l1 = acc[0];
#pragma unroll
    for (int e = 1; e < E_; ++e) if (acc[e] > l1) { l1 = acc[e]; e1 = e; }
    int e2 = -1; float l2 = -3.4e38f;
#pragma unroll
    for (int e = 0; e < E_; ++e) if (e != e1 && acc[e] > l2) { l2 = acc[e]; e2 = e; }
    float d = expf(l2 - l1);
    float inv = 1.f / (1.f + d);
    sel[2 * t] = e1; sel[2 * t + 1] = e2;
    wts[2 * t] = inv; wts[2 * t + 1] = d * inv;
  }
}

// ------------- count: per-block expert histogram (LDS atomics only) -------
__global__ __launch_bounds__(256) void count_k(const int* __restrict__ sel,
                                               int* __restrict__ blockHist) {
  __shared__ int h[E_];
  int t = threadIdx.x;
  if (t < E_) h[t] = 0;
  __syncthreads();
  atomicAdd(&h[sel[blockIdx.x * 256 + t]], 1);
  __syncthreads();
  if (t < E_) blockHist[blockIdx.x * E_ + t] = h[t];
}

// ------------- plan: counts, offsets, per-block scatter bases -------
// ctl[0..7]=counts, ctl[8..15]=offsets.
__global__ __launch_bounds__(64) void plan_k(const int* __restrict__ blockHist,
                                             int* __restrict__ ctl,
                                             int* __restrict__ blockBase) {
  __shared__ int cnts[E_], offs[E_];
  int t = threadIdx.x;
  if (t < E_) {
    int c = 0;
    for (int b = 0; b < NBLK; ++b) c += blockHist[b * E_ + t];
    cnts[t] = c; ctl[t] = c;
  }
  __syncthreads();
  if (t == 0) {
    int off = 0;
    for (int e = 0; e < E_; ++e) { offs[e] = off; ctl[8 + e] = off; off += cnts[e]; }
  }
  __syncthreads();
  if (t < E_) {  // per-block scatter bases: column-wise exclusive scan
    int run = offs[t];
    for (int b = 0; b < NBLK; ++b) {
      blockBase[b * E_ + t] = run;
      run += blockHist[b * E_ + t];
    }
  }
}

// ------------- scatter: deterministic, atomic-free (ballot ranks) -------
__global__ __launch_bounds__(256) void scatter_k(const int* __restrict__ sel,
                                                 const float* __restrict__ wts,
                                                 const int* __restrict__ blockBase,
                                                 int* __restrict__ tok,
                                                 float* __restrict__ sw,
                                                 int* __restrict__ inv) {
  __shared__ int wcnt[4][E_];
  int t = threadIdx.x;
  int lane = t & 63, w = t >> 6;
  int i = blockIdx.x * 256 + t;
  int e = sel[i];
  unsigned long long below = (lane == 63) ? ~0ull >> 1 : (1ull << lane) - 1;
  int myrank = 0;
#pragma unroll
  for (int e0 = 0; e0 < E_; ++e0) {
    unsigned long long m = __ballot(e == e0);
    if (e == e0) myrank = __popcll(m & below);
    if (lane == 0) wcnt[w][e0] = __popcll(m);
  }
  __syncthreads();
  int pos = blockBase[blockIdx.x * E_ + e] + myrank;
#pragma unroll
  for (int w2 = 0; w2 < 3; ++w2)
    if (w2 < w) pos += wcnt[w2][e];
  tok[pos] = i >> 1;
  sw[pos] = wts[i];
  inv[i] = pos;
}

// ---------------- GEMM1: act = silu(Xg @ Wg^T) * (Xg @ Wu^T) ----------------
// R2 champion: 128 token-rows x 64 j (gate+up panels), BK=64, 4 waves (2x2),
// 2-phase dbuf, 64KB LDS -> 2 blocks/CU. Expert-per-XCD, m outer, j inner.
__global__ __launch_bounds__(256) void gemm1_k(const bf16* __restrict__ Xb,
                                               const bf16* __restrict__ Wgu,
                                               const int* __restrict__ ctl,
                                               const int* __restrict__ tok,
                                               bf16* __restrict__ act) {
  constexpr int NJ = I_ / 64;        // 22
  constexpr int NM = T_ / 128;       // 64
  constexpr int NB = NJ * NM * E_;   // 11264
  const int L0 = ((int)blockIdx.x & 7) * (NB >> 3) + ((int)blockIdx.x >> 3);
  const int e = L0 / (NJ * NM);
  const int rem = L0 - e * (NJ * NM);
  const int m0 = (rem / NJ) * 128;   // m outer, j inner -> A-tile L2-hot
  const int j0 = (rem % NJ) * 64;
  const int cnt = ctl[e];
  if (m0 >= cnt) return;
  const int base = ctl[8 + e];

  __shared__ alignas(16) bf16 lA[2][128 * 64];
  __shared__ alignas(16) bf16 lBg[2][64 * 64];
  __shared__ alignas(16) bf16 lBu[2][64 * 64];

  const int t = threadIdx.x;
  const int lane = t & 63;
  const int wr = (t >> 7) & 1;
  const int wc = (t >> 6) & 1;
  const int lo = lane & 15, hi = lane >> 4;
  const bf16* wg = Wgu + (size_t)e * (2 * I_) * H_;

  // staging; XOR swizzle on the GLOBAL source chunk, LDS dest linear
  const bf16* asrc[4]; int aoff[4];
#pragma unroll
  for (int c = 0; c < 4; ++c) {
    int L = c * 256 + t;
    int row = L >> 3, cc = (L & 7) ^ (row & 7);
    int r = m0 + row; if (r >= cnt) r = cnt - 1;
    asrc[c] = Xb + (size_t)tok[base + r] * H_ + cc * 8;
    aoff[c] = L * 16;
  }
  const bf16* gsrc[2]; const bf16* usrc[2]; int boff[2];
#pragma unroll
  for (int c = 0; c < 2; ++c) {
    int L = c * 256 + t;
    int row = L >> 3, cc = (L & 7) ^ (row & 7);
    gsrc[c] = wg + (size_t)(j0 + row) * H_ + cc * 8;
    usrc[c] = wg + (size_t)(I_ + j0 + row) * H_ + cc * 8;
    boff[c] = L * 16;
  }

#define STG1(b, k)                                                \
  {                                                               \
    _Pragma("unroll")                                             \
    for (int c = 0; c < 4; ++c)                                   \
      gl2lds16(asrc[c] + (k), (char*)lA[b] + aoff[c]);            \
    _Pragma("unroll")                                             \
    for (int c = 0; c < 2; ++c) {                                 \
      gl2lds16(gsrc[c] + (k), (char*)lBg[b] + boff[c]);           \
      gl2lds16(usrc[c] + (k), (char*)lBu[b] + boff[c]);           \
    }                                                             \
  }

  f32x4 zero = {0.f, 0.f, 0.f, 0.f};
  f32x4 ag[4][2], au[4][2];
#pragma unroll
  for (int m = 0; m < 4; ++m)
#pragma unroll
    for (int n = 0; n < 2; ++n) { ag[m][n] = zero; au[m][n] = zero; }

  STG1(0, 0);
  __syncthreads();

  for (int k0 = 0; k0 < H_; k0 += 128) {
#pragma unroll
    for (int p = 0; p < 2; ++p) {
      const int kc = k0 + p * 64;
      if (kc + 64 < H_) STG1(p ^ 1, kc + 64);   // prefetch next K-tile
#pragma unroll
      for (int kk = 0; kk < 2; ++kk) {
        const int chunk = kk * 4 + hi;
        bf16x8 af[4], bg[2], bu[2];
#pragma unroll
        for (int m = 0; m < 4; ++m) {
          int row = wr * 64 + m * 16 + lo;
          af[m] = *(const bf16x8*)((const char*)lA[p] + row * 128 + ((chunk ^ (row & 7)) * 16));
        }
#pragma unroll
        for (int n = 0; n < 2; ++n) {
          int row = wc * 32 + n * 16 + lo;
          int sw2 = (chunk ^ (row & 7)) * 16;
          bg[n] = *(const bf16x8*)((const char*)lBg[p] + row * 128 + sw2);
          bu[n] = *(const bf16x8*)((const char*)lBu[p] + row * 128 + sw2);
        }
#pragma unroll
        for (int m = 0; m < 4; ++m)
#pragma unroll
          for (int n = 0; n < 2; ++n) {
            ag[m][n] = __builtin_amdgcn_mfma_f32_16x16x32_bf16(af[m], bg[n], ag[m][n], 0, 0, 0);
            au[m][n] = __builtin_amdgcn_mfma_f32_16x16x32_bf16(af[m], bu[n], au[m][n], 0, 0, 0);
          }
      }
      __syncthreads();
    }
  }
#undef STG1

#pragma unroll
  for (int m = 0; m < 4; ++m)
#pragma unroll
    for (int r = 0; r < 4; ++r) {
      int row = m0 + wr * 64 + m * 16 + hi * 4 + r;
      if (row < cnt) {
        bf16* dst = act + (size_t)(base + row) * I_ + j0 + wc * 32 + lo;
#pragma unroll
        for (int n = 0; n < 2; ++n) {
          float g = ag[m][n][r], u = au[m][n][r];
          dst[n * 16] = (bf16)(g / (1.f + __expf(-g)) * u);
        }
      }
    }
}

// ---------------- GEMM2: y[slot] = w * (act @ Wd^T), bf16, no atomics ------
// 128 slot-rows x 128 H-cols, BK=64, 4 waves (2x2), 2-phase dbuf, 64KB LDS.
// Expert-per-XCD static grid, m outer, n inner (act-tile L2-hot).
__global__ __launch_bounds__(256) void gemm2_k(const bf16* __restrict__ act,
                                               const bf16* __restrict__ Wd,
                                               const int* __restrict__ ctl,
                                               const float* __restrict__ sw,
                                               bf16* __restrict__ y) {
  constexpr int NJ = H_ / 128;       // 16
  constexpr int NM = T_ / 128;       // 64
  constexpr int NB = NJ * NM * E_;   // 8192
  const int L0 = ((int)blockIdx.x & 7) * (NB >> 3) + ((int)blockIdx.x >> 3);
  const int e = L0 / (NJ * NM);
  const int rem = L0 - e * (NJ * NM);
  const int m0 = (rem / NJ) * 128;
  const int n0 = (rem % NJ) * 128;
  const int cnt = ctl[e];
  if (m0 >= cnt) return;
  const int base = ctl[8 + e];

  __shared__ alignas(16) bf16 lA[2][128 * 64];
  __shared__ alignas(16) bf16 lB[2][128 * 64];

  const int t = threadIdx.x;
  const int lane = t & 63;
  const int wr = (t >> 7) & 1;
  const int wc = (t >> 6) & 1;
  const int lo = lane & 15, hi = lane >> 4;
  const bf16* wd = Wd + (size_t)e * H_ * I_;

  const bf16* asrc[4]; int aoff[4];
#pragma unroll
  for (int c = 0; c < 4; ++c) {
    int L = c * 256 + t;
    int row = L >> 3, cc = (L & 7) ^ (row & 7);
    int r = m0 + row; if (r >= cnt) r = cnt - 1;
    asrc[c] = act + (size_t)(base + r) * I_ + cc * 8;
    aoff[c] = L * 16;
  }
  const bf16* bsrc[4]; int boff[4];
#pragma unroll
  for (int c = 0; c < 4; ++c) {
    int L = c * 256 + t;
    int row = L >> 3, cc = (L & 7) ^ (row & 7);
    bsrc[c] = wd + (size_t)(n0 + row) * I_ + cc * 8;
    boff[c] = L * 16;
  }

#define STG2(b, k)                                                \
  {                                                               \
    _Pragma("unroll")                                             \
    for (int c = 0; c < 4; ++c)                                   \
      gl2lds16(asrc[c] + (k), (char*)lA[b] + aoff[c]);            \
    _Pragma("unroll")                                             \
    for (int c = 0; c < 4; ++c)                                   \
      gl2lds16(bsrc[c] + (k), (char*)lB[b] + boff[c]);            \
  }

  f32x4 zero = {0.f, 0.f, 0.f, 0.f};
  f32x4 acc[4][4];
#pragma unroll
  for (int m = 0; m < 4; ++m)
#pragma unroll
    for (int n = 0; n < 4; ++n) acc[m][n] = zero;

  STG2(0, 0);
  __syncthreads();

  for (int k0 = 0; k0 < I_; k0 += 128) {
#pragma unroll
    for (int p = 0; p < 2; ++p) {
      const int kc = k0 + p * 64;
      if (kc + 64 < I_) STG2(p ^ 1, kc + 64);
#pragma unroll
      for (int kk = 0; kk < 2; ++kk) {
        const int chunk = kk * 4 + hi;
        bf16x8 af[4], bb[4];
#pragma unroll
        for (int m = 0; m < 4; ++m) {
          int row = wr * 64 + m * 16 + lo;
          af[m] = *(const bf16x8*)((const char*)lA[p] + row * 128 + ((chunk ^ (row & 7)) * 16));
        }
#pragma unroll
        for (int n = 0; n < 4; ++n) {
          int row = wc * 64 + n * 16 + lo;
          bb[n] = *(const bf16x8*)((const char*)lB[p] + row * 128 + ((chunk ^ (row & 7)) * 16));
        }
#pragma unroll
        for (int m = 0; m < 4; ++m)
#pragma unroll
          for (int n = 0; n < 4; ++n)
            acc[m][n] = __builtin_amdgcn_mfma_f32_16x16x32_bf16(af[m], bb[n], acc[m][n], 0, 0, 0);
      }
      __syncthreads();
    }
  }
#undef STG2

#pragma unroll
  for (int m = 0; m < 4; ++m)
#pragma unroll
    for (int r = 0; r < 4; ++r) {
      int row = m0 + wr * 64 + m * 16 + hi * 4 + r;
      if (row < cnt) {
        float w = sw[base + row];
        bf16* dst = y + (size_t)(base + row) * H_ + n0 + wc * 64 + lo;
#pragma unroll
        for (int n = 0; n < 4; ++n) dst[n * 16] = (bf16)(w * acc[m][n][r]);
      }
    }
}

// ---------------- combine: out[t] = y[inv[2t]] + y[inv[2t+1]] ----------------
__global__ __launch_bounds__(256) void combine_k(const bf16* __restrict__ y,
                                                 const int* __restrict__ inv,
                                                 float* __restrict__ out) {
  int idx = blockIdx.x * 256 + threadIdx.x;  // one bf16x8 chunk per thread
  int t = idx >> 8;                          // H_/8 = 256 chunks per token
  int c = idx & 255;
  int i1 = inv[2 * t], i2 = inv[2 * t + 1];
  bf16x8 a = *((const bf16x8*)(y + (size_t)i1 * H_) + c);
  bf16x8 b = *((const bf16x8*)(y + (size_t)i2 * H_) + c);
  float* op = out + (size_t)t * H_ + c * 8;
#pragma unroll
  for (int k = 0; k < 8; ++k) op[k] = (float)a[k] + (float)b[k];
}

// ---------------- host launch ----------------
extern "C" void kernel_launch(void* const* d_in, const int* in_sizes, int n_in,
                              void* d_out, int out_size, void* d_ws, size_t ws_size,
                              hipStream_t stream) {
  const float* X = (const float*)d_in[0];
  const float* R = (const float*)d_in[1];
  const float* Wgu = (const float*)d_in[2];
  const float* Wd = (const float*)d_in[3];
  float* out = (float*)d_out;

  char* ws = (char*)d_ws;
  size_t o = 0;
  auto alloc = [&](size_t sz) { void* p = ws + o; o += (sz + 255) & ~(size_t)255; return p; };
  bf16* wgu_bf = (bf16*)alloc(sizeof(bf16) * (size_t)E_ * 2 * I_ * H_);
  bf16* wd_bf  = (bf16*)alloc(sizeof(bf16) * (size_t)E_ * H_ * I_);
  bf16* xbf    = (bf16*)alloc(sizeof(bf16) * (size_t)T_ * H_);
  bf16* actb   = (bf16*)alloc(sizeof(bf16) * (size_t)NSLOT * I_);
  int* sel     = (int*)alloc(4 * NSLOT);
  float* wts   = (float*)alloc(4 * NSLOT);
  int* tokb    = (int*)alloc(4 * NSLOT);
  float* swb   = (float*)alloc(4 * NSLOT);
  int* invb    = (int*)alloc(4 * NSLOT);
  int* ctl     = (int*)alloc(4 * 32);
  int* bh      = (int*)alloc(4 * NBLK * E_);
  int* bb      = (int*)alloc(4 * NBLK * E_);
  // y (NSLOT x H bf16, 67 MB) aliases wgu_bf (92 MB), dead after gemm1
  bf16* yb = wgu_bf;

  cvtw_k<<<2048, 256, 0, stream>>>(Wgu, (int)((size_t)E_ * 2 * I_ * H_ / 8),
                                   Wd, (int)((size_t)E_ * H_ * I_ / 8),
                                   wgu_bf, wd_bf);
  router_k<<<T_ / 4, 256, 0, stream>>>(X, R, xbf, sel, wts);
  count_k<<<NBLK, 256, 0, stream>>>(sel, bh);
  plan_k<<<1, 64, 0, stream>>>(bh, ctl, bb);
  scatter_k<<<NBLK, 256, 0, stream>>>(sel, wts, bb, tokb, swb, invb);
  gemm1_k<<<(I_ / 64) * (T_ / 128) * E_, 256, 0, stream>>>(xbf, wgu_bf, ctl, tokb, actb);
  gemm2_k<<<(H_ / 128) * (T_ / 128) * E_, 256, 0, stream>>>(actb, wd_bf, ctl, swb, yb);
  combine_k<<<T_ * H_ / 2048, 256, 0, stream>>>(yb, invb, out);
}